// Round 4
// baseline (309.351 us; speedup 1.0000x reference)
//
#include <hip/hip_runtime.h>
#include <hip/hip_fp16.h>

// GCN 2-layer: N=50000 nodes, E=800000 edges, 128 -> 128(relu) -> 64
// CSR-by-dst -> h' = dinv*(x@W) via split-bf16 MFMA, written as fp16 in
// channel-sliced blocked layout hs[slice][node][32] (3.2MB/slice = L2-resident)
// -> XCD-pinned sliced gather aggregate (wave = 4 edges x 16 lanes),
// butterfly reduce, final dinv*sum + bias (+relu).

#define N_NODES 50000
#define N_EDGES 800000

typedef __bf16 bf16x8 __attribute__((ext_vector_type(8)));
typedef float  f32x4  __attribute__((ext_vector_type(4)));

// ---------------- CSR build ----------------

__global__ void count_kernel(const int* __restrict__ dst, int* __restrict__ deg) {
    int e = blockIdx.x * 256 + threadIdx.x;
    if (e < N_EDGES) atomicAdd(&deg[dst[e]], 1);
}

__global__ void scan_part_kernel(const int* __restrict__ deg, int* __restrict__ partials) {
    __shared__ int red[256];
    int tid = threadIdx.x;
    int base = blockIdx.x * 1024 + tid * 4;
    int s = 0;
#pragma unroll
    for (int i = 0; i < 4; i++) { int idx = base + i; if (idx < N_NODES) s += deg[idx]; }
    red[tid] = s; __syncthreads();
    for (int off = 128; off > 0; off >>= 1) {
        if (tid < off) red[tid] += red[tid + off];
        __syncthreads();
    }
    if (tid == 0) partials[blockIdx.x] = red[0];
}

__global__ void scan_blocks_kernel(int* partials, int nb) {
    int tid = threadIdx.x;            // 64 threads, one wave
    int orig = (tid < nb) ? partials[tid] : 0;
    int v = orig;
    for (int off = 1; off < 64; off <<= 1) {
        int t = __shfl_up(v, off, 64);
        if (tid >= off) v += t;
    }
    if (tid < nb) partials[tid] = v - orig;   // exclusive
}

__global__ void scan_final_kernel(const int* __restrict__ deg, const int* __restrict__ poff,
                                  int* __restrict__ row_off, int* __restrict__ cursor,
                                  float* __restrict__ dinv) {
    __shared__ int sc[256];
    int tid = threadIdx.x;
    int base = blockIdx.x * 1024 + tid * 4;
    int v[4]; int s = 0;
#pragma unroll
    for (int i = 0; i < 4; i++) { int idx = base + i; v[i] = (idx < N_NODES) ? deg[idx] : 0; s += v[i]; }
    sc[tid] = s; __syncthreads();
    for (int off = 1; off < 256; off <<= 1) {
        int t = (tid >= off) ? sc[tid - off] : 0;
        __syncthreads();
        sc[tid] += t;
        __syncthreads();
    }
    int run = sc[tid] - s + poff[blockIdx.x];
#pragma unroll
    for (int i = 0; i < 4; i++) {
        int idx = base + i;
        if (idx < N_NODES) {
            row_off[idx] = run;
            cursor[idx]  = run;
            dinv[idx]    = rsqrtf((float)(v[i] + 1));   // +1 self-loop
            run += v[i];
        }
    }
}

__global__ void fill_kernel(const int* __restrict__ src, const int* __restrict__ dst,
                            int* __restrict__ cursor, int* __restrict__ ssrc) {
    int e = blockIdx.x * 256 + threadIdx.x;
    if (e < N_EDGES) {
        int d = dst[e];
        int p = atomicAdd(&cursor[d], 1);
        ssrc[p] = src[e];
    }
}

// ---------------- W prep: f32 [K=128][N] -> hi/lo bf16 B-fragments ----------------
template<int N>
__global__ void wprep_kernel(const float* __restrict__ W,
                             __bf16* __restrict__ hi, __bf16* __restrict__ lo) {
    int idx = blockIdx.x * 256 + threadIdx.x;     // total (N/16)*4*64
    if (idx >= (N / 16) * 4 * 64) return;
    int l = idx & 63;
    int s = (idx >> 6) & 3;
    int c = idx >> 8;
    int n = c * 16 + (l & 15);
    int k0 = s * 32 + (l >> 4) * 8;
#pragma unroll
    for (int j = 0; j < 8; j++) {
        float w = W[(k0 + j) * N + n];
        __bf16 h = (__bf16)w;
        hi[idx * 8 + j] = h;
        lo[idx * 8 + j] = (__bf16)(w - (float)h);
    }
}

// ---------------- GEMM: hs[slice][row][32] = fp16( dinv[row] * (X @ W)[row] ) ----------
// split-bf16 MFMA (3 terms), A-frags straight from global X rows.
template<int OUTC>
__global__ __launch_bounds__(256) void gemm_mfma_kernel(
        const float* __restrict__ X, const __bf16* __restrict__ Whi,
        const __bf16* __restrict__ Wlo, const float* __restrict__ dinv,
        __half* __restrict__ hs) {
    constexpr int NC = OUTC / 16;
    int tid = threadIdx.x;
    int w = tid >> 6, lane = tid & 63;
    int q = lane >> 4, lr = lane & 15;
    int rb = blockIdx.x * 64 + w * 16;
    int row = rb + lr;
    int rowc = (row < N_NODES) ? row : (N_NODES - 1);

    f32x4 acc[NC];
#pragma unroll
    for (int c = 0; c < NC; c++) acc[c] = (f32x4){0.f, 0.f, 0.f, 0.f};

#pragma unroll
    for (int s = 0; s < 4; s++) {
        const float* xp = X + (size_t)rowc * 128 + s * 32 + q * 8;
        float4 x0 = *(const float4*)xp;
        float4 x1 = *(const float4*)(xp + 4);
        float xv[8] = {x0.x, x0.y, x0.z, x0.w, x1.x, x1.y, x1.z, x1.w};
        bf16x8 a_hi, a_lo;
#pragma unroll
        for (int j = 0; j < 8; j++) {
            __bf16 h = (__bf16)xv[j];
            a_hi[j] = h;
            a_lo[j] = (__bf16)(xv[j] - (float)h);
        }
#pragma unroll
        for (int c = 0; c < NC; c++) {
            size_t fo = (size_t)((c * 4 + s) * 64 + lane) * 8;
            bf16x8 bh = *(const bf16x8*)(Whi + fo);
            bf16x8 bl = *(const bf16x8*)(Wlo + fo);
            acc[c] = __builtin_amdgcn_mfma_f32_16x16x32_bf16(a_hi, bh, acc[c], 0, 0, 0);
            acc[c] = __builtin_amdgcn_mfma_f32_16x16x32_bf16(a_lo, bh, acc[c], 0, 0, 0);
            acc[c] = __builtin_amdgcn_mfma_f32_16x16x32_bf16(a_hi, bl, acc[c], 0, 0, 0);
        }
    }

    // C/D layout: col = c*16 + lr, row(within 16) = q*4 + r
    // hs blocked: slice = ch>>5 (= c>>1), within-slice ch = (c&1)*16 + lr
#pragma unroll
    for (int r = 0; r < 4; r++) {
        int grow = rb + q * 4 + r;
        if (grow < N_NODES) {
            float sc = dinv[grow];
#pragma unroll
            for (int c = 0; c < NC; c++) {
                __half* hp = hs + (size_t)(c >> 1) * N_NODES * 32
                                + (size_t)grow * 32 + (c & 1) * 16 + lr;
                *hp = __float2half(acc[c][r] * sc);
            }
        }
    }
}

// ---------------- Sliced aggregate ----------------
// hs: fp16 blocked [NSLICE][N_NODES][32]; out f32 [N_NODES][OUTC], ch = slice*32..+32.
// blockIdx%8 pins (slice,part) regions to XCDs: the 3.2MB slice table stays
// L2-resident per XCD. Wave = one node: 4 edge-lanes x 16 ch-pair lanes,
// butterfly shfl_xor(16,32) reduce. Tail: clamp index + predicated add.
template<int NSLICE, int NPART, int OUTC, bool RELU>
__global__ __launch_bounds__(256) void aggregate_sliced_kernel(
        const __half* __restrict__ hs, const int* __restrict__ row_off,
        const int* __restrict__ deg, const int* __restrict__ ssrc,
        const float* __restrict__ dinv, const float* __restrict__ bias,
        float* __restrict__ out) {
    constexpr int NODES_PER_PART = N_NODES / NPART;
    int region = blockIdx.x & 7;
    int rblk   = blockIdx.x >> 3;
    int slice, part;
    if constexpr (NSLICE == 4) { slice = region >> 1; part = region & 1; }
    else                       { slice = region & 1;  part = region >> 1; }
    int wave = threadIdx.x >> 6;
    int lane = threadIdx.x & 63;
    int node = part * NODES_PER_PART + rblk * 4 + wave;

    const __half* sb = hs + (size_t)slice * N_NODES * 32;
    int beg  = row_off[node];
    int d    = deg[node];
    float di = dinv[node];
    int g  = lane >> 4;      // edge sub-group 0..3
    int cp = lane & 15;      // channel pair 0..15

    float2 self = __half22float2(*((const __half2*)(sb + (size_t)node * 32) + cp));
    float2 bv   = ((const float2*)(bias + slice * 32))[cp];

    float2 acc = make_float2(0.f, 0.f);
    for (int j = 0; j < d; j += 8) {
        int i0 = j + g, i1 = j + 4 + g;
        int s0 = ssrc[beg + ((i0 < d) ? i0 : (d - 1))];
        int s1 = ssrc[beg + ((i1 < d) ? i1 : (d - 1))];
        float2 v0 = __half22float2(*((const __half2*)(sb + (size_t)s0 * 32) + cp));
        float2 v1 = __half22float2(*((const __half2*)(sb + (size_t)s1 * 32) + cp));
        if (i0 < d) { acc.x += v0.x; acc.y += v0.y; }
        if (i1 < d) { acc.x += v1.x; acc.y += v1.y; }
    }
    acc.x += __shfl_xor(acc.x, 16, 64);
    acc.x += __shfl_xor(acc.x, 32, 64);
    acc.y += __shfl_xor(acc.y, 16, 64);
    acc.y += __shfl_xor(acc.y, 32, 64);
    acc.x += self.x; acc.y += self.y;

    float ox = fmaf(di, acc.x, bv.x);
    float oy = fmaf(di, acc.y, bv.y);
    if (RELU) { ox = fmaxf(ox, 0.f); oy = fmaxf(oy, 0.f); }
    if (lane < 16) {
        ((float2*)(out + (size_t)node * OUTC + slice * 32))[cp] = make_float2(ox, oy);
    }
}

// ---------------- launch ----------------

extern "C" void kernel_launch(void* const* d_in, const int* in_sizes, int n_in,
                              void* d_out, int out_size, void* d_ws, size_t ws_size,
                              hipStream_t stream) {
    const float* x  = (const float*)d_in[0];   // [N,128]
    const int*   ei = (const int*)d_in[1];     // [2,E]
    const float* W1 = (const float*)d_in[2];   // [128,128]
    const float* b1 = (const float*)d_in[3];   // [128]
    const float* W2 = (const float*)d_in[4];   // [128,64]
    const float* b2 = (const float*)d_in[5];   // [64]
    float* out = (float*)d_out;                // [N,64]

    const int* src = ei;
    const int* dst = ei + N_EDGES;

    char* p = (char*)d_ws;
    size_t off = 0;
    auto alloc = [&](size_t bytes) { void* q = p + off; off += (bytes + 255) & ~(size_t)255; return q; };
    float*  dinv    = (float*) alloc(N_NODES * 4);
    int*    deg     = (int*)   alloc(N_NODES * 4);
    int*    row_off = (int*)   alloc(N_NODES * 4);
    int*    cursor  = (int*)   alloc(N_NODES * 4);
    int*    parts   = (int*)   alloc(64 * 4);
    int*    ssrc    = (int*)   alloc(N_EDGES * 4);
    __bf16* w1hi    = (__bf16*)alloc(128 * 128 * 2);
    __bf16* w1lo    = (__bf16*)alloc(128 * 128 * 2);
    __bf16* w2hi    = (__bf16*)alloc(128 * 64 * 2);
    __bf16* w2lo    = (__bf16*)alloc(128 * 64 * 2);
    __half* hs1     = (__half*)alloc((size_t)N_NODES * 128 * 2);  // [4][N][32]
    __half* hs2     = (__half*)alloc((size_t)N_NODES * 64 * 2);   // [2][N][32]
    float*  x2      = (float*) alloc((size_t)N_NODES * 128 * 4);

    const int nb_scan = (N_NODES + 1023) / 1024;       // 49

    hipMemsetAsync(deg, 0, N_NODES * sizeof(int), stream);
    count_kernel<<<(N_EDGES + 255) / 256, 256, 0, stream>>>(dst, deg);
    scan_part_kernel<<<nb_scan, 256, 0, stream>>>(deg, parts);
    scan_blocks_kernel<<<1, 64, 0, stream>>>(parts, nb_scan);
    scan_final_kernel<<<nb_scan, 256, 0, stream>>>(deg, parts, row_off, cursor, dinv);
    fill_kernel<<<(N_EDGES + 255) / 256, 256, 0, stream>>>(src, dst, cursor, ssrc);

    wprep_kernel<128><<<8, 256, 0, stream>>>(W1, w1hi, w1lo);
    wprep_kernel<64> <<<4, 256, 0, stream>>>(W2, w2hi, w2lo);

    // layer 1: hs1 = fp16(dinv*(x@W1)); x2 = relu(dinv*(self+sum) + b1)
    gemm_mfma_kernel<128><<<(N_NODES + 63) / 64, 256, 0, stream>>>(x, w1hi, w1lo, dinv, hs1);
    aggregate_sliced_kernel<4, 2, 128, true><<<8 * (N_NODES / 2 / 4), 256, 0, stream>>>(
        hs1, row_off, deg, ssrc, dinv, b1, x2);

    // layer 2: hs2 = fp16(dinv*(x2@W2)); out = dinv*(self+sum) + b2
    gemm_mfma_kernel<64><<<(N_NODES + 63) / 64, 256, 0, stream>>>(x2, w2hi, w2lo, dinv, hs2);
    aggregate_sliced_kernel<2, 4, 64, false><<<8 * (N_NODES / 4 / 4), 256, 0, stream>>>(
        hs2, row_off, deg, ssrc, dinv, b2, out);
}

// Round 5
// 269.444 us; speedup vs baseline: 1.1481x; 1.1481x over previous
//
#include <hip/hip_runtime.h>
#include <hip/hip_fp16.h>

// GCN 2-layer: N=50000 nodes, E=800000 edges, 128 -> 128(relu) -> 64
// CSR-by-dst -> h' = dinv*(x@W) via split-bf16 MFMA written as flat fp16
// [N][C] -> wave-per-node gather aggregate (full fp16 row per wave-instr,
// 8 rows in flight), f32 accumulate, final dinv*sum + bias (+relu).
// R4 lesson: channel-sliced L2-pinning killed FETCH (186->25MB) but tripled
// per-edge instruction cost (4B/lane gathers, 4x waves) -> net regression.
// This round: R3 structure + fp16 table = half the bytes at R3's instr cost.

#define N_NODES 50000
#define N_EDGES 800000

typedef __bf16 bf16x8 __attribute__((ext_vector_type(8)));
typedef float  f32x4  __attribute__((ext_vector_type(4)));

// ---------------- CSR build ----------------

__global__ void count_kernel(const int* __restrict__ dst, int* __restrict__ deg) {
    int e = blockIdx.x * 256 + threadIdx.x;
    if (e < N_EDGES) atomicAdd(&deg[dst[e]], 1);
}

__global__ void scan_part_kernel(const int* __restrict__ deg, int* __restrict__ partials) {
    __shared__ int red[256];
    int tid = threadIdx.x;
    int base = blockIdx.x * 1024 + tid * 4;
    int s = 0;
#pragma unroll
    for (int i = 0; i < 4; i++) { int idx = base + i; if (idx < N_NODES) s += deg[idx]; }
    red[tid] = s; __syncthreads();
    for (int off = 128; off > 0; off >>= 1) {
        if (tid < off) red[tid] += red[tid + off];
        __syncthreads();
    }
    if (tid == 0) partials[blockIdx.x] = red[0];
}

__global__ void scan_blocks_kernel(int* partials, int nb) {
    int tid = threadIdx.x;            // 64 threads, one wave
    int orig = (tid < nb) ? partials[tid] : 0;
    int v = orig;
    for (int off = 1; off < 64; off <<= 1) {
        int t = __shfl_up(v, off, 64);
        if (tid >= off) v += t;
    }
    if (tid < nb) partials[tid] = v - orig;   // exclusive
}

__global__ void scan_final_kernel(const int* __restrict__ deg, const int* __restrict__ poff,
                                  int* __restrict__ row_off, int* __restrict__ cursor,
                                  float* __restrict__ dinv) {
    __shared__ int sc[256];
    int tid = threadIdx.x;
    int base = blockIdx.x * 1024 + tid * 4;
    int v[4]; int s = 0;
#pragma unroll
    for (int i = 0; i < 4; i++) { int idx = base + i; v[i] = (idx < N_NODES) ? deg[idx] : 0; s += v[i]; }
    sc[tid] = s; __syncthreads();
    for (int off = 1; off < 256; off <<= 1) {
        int t = (tid >= off) ? sc[tid - off] : 0;
        __syncthreads();
        sc[tid] += t;
        __syncthreads();
    }
    int run = sc[tid] - s + poff[blockIdx.x];
#pragma unroll
    for (int i = 0; i < 4; i++) {
        int idx = base + i;
        if (idx < N_NODES) {
            row_off[idx] = run;
            cursor[idx]  = run;
            dinv[idx]    = rsqrtf((float)(v[i] + 1));   // +1 self-loop
            run += v[i];
        }
    }
}

__global__ void fill_kernel(const int* __restrict__ src, const int* __restrict__ dst,
                            int* __restrict__ cursor, int* __restrict__ ssrc) {
    int e = blockIdx.x * 256 + threadIdx.x;
    if (e < N_EDGES) {
        int d = dst[e];
        int p = atomicAdd(&cursor[d], 1);
        ssrc[p] = src[e];
    }
}

// ---------------- W prep: f32 [K=128][N] -> hi/lo bf16 B-fragments ----------------
template<int N>
__global__ void wprep_kernel(const float* __restrict__ W,
                             __bf16* __restrict__ hi, __bf16* __restrict__ lo) {
    int idx = blockIdx.x * 256 + threadIdx.x;     // total (N/16)*4*64
    if (idx >= (N / 16) * 4 * 64) return;
    int l = idx & 63;
    int s = (idx >> 6) & 3;
    int c = idx >> 8;
    int n = c * 16 + (l & 15);
    int k0 = s * 32 + (l >> 4) * 8;
#pragma unroll
    for (int j = 0; j < 8; j++) {
        float w = W[(k0 + j) * N + n];
        __bf16 h = (__bf16)w;
        hi[idx * 8 + j] = h;
        lo[idx * 8 + j] = (__bf16)(w - (float)h);
    }
}

// ---------------- GEMM: hs[row][OUTC] = fp16( dinv[row] * (X @ W)[row] ) ----------
// split-bf16 MFMA (3 terms), A-frags straight from global X rows.
template<int OUTC>
__global__ __launch_bounds__(256) void gemm_mfma_kernel(
        const float* __restrict__ X, const __bf16* __restrict__ Whi,
        const __bf16* __restrict__ Wlo, const float* __restrict__ dinv,
        __half* __restrict__ hs) {
    constexpr int NC = OUTC / 16;
    int tid = threadIdx.x;
    int w = tid >> 6, lane = tid & 63;
    int q = lane >> 4, lr = lane & 15;
    int rb = blockIdx.x * 64 + w * 16;
    int row = rb + lr;
    int rowc = (row < N_NODES) ? row : (N_NODES - 1);

    f32x4 acc[NC];
#pragma unroll
    for (int c = 0; c < NC; c++) acc[c] = (f32x4){0.f, 0.f, 0.f, 0.f};

#pragma unroll
    for (int s = 0; s < 4; s++) {
        const float* xp = X + (size_t)rowc * 128 + s * 32 + q * 8;
        float4 x0 = *(const float4*)xp;
        float4 x1 = *(const float4*)(xp + 4);
        float xv[8] = {x0.x, x0.y, x0.z, x0.w, x1.x, x1.y, x1.z, x1.w};
        bf16x8 a_hi, a_lo;
#pragma unroll
        for (int j = 0; j < 8; j++) {
            __bf16 h = (__bf16)xv[j];
            a_hi[j] = h;
            a_lo[j] = (__bf16)(xv[j] - (float)h);
        }
#pragma unroll
        for (int c = 0; c < NC; c++) {
            size_t fo = (size_t)((c * 4 + s) * 64 + lane) * 8;
            bf16x8 bh = *(const bf16x8*)(Whi + fo);
            bf16x8 bl = *(const bf16x8*)(Wlo + fo);
            acc[c] = __builtin_amdgcn_mfma_f32_16x16x32_bf16(a_hi, bh, acc[c], 0, 0, 0);
            acc[c] = __builtin_amdgcn_mfma_f32_16x16x32_bf16(a_lo, bh, acc[c], 0, 0, 0);
            acc[c] = __builtin_amdgcn_mfma_f32_16x16x32_bf16(a_hi, bl, acc[c], 0, 0, 0);
        }
    }

    // C/D layout: col = c*16 + lr, row(within 16) = q*4 + r
#pragma unroll
    for (int r = 0; r < 4; r++) {
        int grow = rb + q * 4 + r;
        if (grow < N_NODES) {
            float sc = dinv[grow];
#pragma unroll
            for (int c = 0; c < NC; c++) {
                hs[(size_t)grow * OUTC + c * 16 + lr] = __float2half(acc[c][r] * sc);
            }
        }
    }
}

// ---------------- Aggregate CH=128: wave per node, half2/lane = full 256B row -------
template<bool RELU>
__global__ __launch_bounds__(256) void aggregate128_kernel(
        const __half* __restrict__ hs, const int* __restrict__ row_off,
        const int* __restrict__ deg, const int* __restrict__ ssrc,
        const float* __restrict__ dinv, const float* __restrict__ bias,
        float* __restrict__ out) {
    int node = (blockIdx.x * 256 + threadIdx.x) >> 6;
    int lane = threadIdx.x & 63;
    if (node >= N_NODES) return;
    int beg = row_off[node];
    int d   = deg[node];
    float di = dinv[node];
    const __half2* Hv = (const __half2*)hs;      // [N][64] half2
    float2 acc = __half22float2(Hv[(size_t)node * 64 + lane]);   // self-loop
    for (int j = 0; j < d; j += 8) {
        int s[8]; __half2 v[8];
#pragma unroll
        for (int u = 0; u < 8; u++) {
            int i = j + u;
            s[u] = ssrc[beg + ((i < d) ? i : (d - 1))];
        }
#pragma unroll
        for (int u = 0; u < 8; u++) v[u] = Hv[(size_t)s[u] * 64 + lane];
#pragma unroll
        for (int u = 0; u < 8; u++) {
            if (j + u < d) {
                float2 f = __half22float2(v[u]);
                acc.x += f.x; acc.y += f.y;
            }
        }
    }
    float2 b = ((const float2*)bias)[lane];
    float ox = fmaf(di, acc.x, b.x);
    float oy = fmaf(di, acc.y, b.y);
    if (RELU) { ox = fmaxf(ox, 0.f); oy = fmaxf(oy, 0.f); }
    ((float2*)out)[(size_t)node * 64 + lane] = make_float2(ox, oy);
}

// ---------------- Aggregate CH=64: wave per node, 2 edges per gather instr ----------
// lanes split: half = lane>>5 (edge parity), cp = lane&31 (channel pair).
// 16 edges per iteration = 8 gathers in flight; fold halves via shfl_xor(32).
__global__ __launch_bounds__(256) void aggregate64_kernel(
        const __half* __restrict__ hs, const int* __restrict__ row_off,
        const int* __restrict__ deg, const int* __restrict__ ssrc,
        const float* __restrict__ dinv, const float* __restrict__ bias,
        float* __restrict__ out) {
    int node = (blockIdx.x * 256 + threadIdx.x) >> 6;
    int lane = threadIdx.x & 63;
    if (node >= N_NODES) return;
    int beg = row_off[node];
    int d   = deg[node];
    float di = dinv[node];
    int half = lane >> 5, cp = lane & 31;
    const __half2* Hv = (const __half2*)hs;      // [N][32] half2
    float2 acc = make_float2(0.f, 0.f);
    for (int j = 0; j < d; j += 16) {
        int s[8]; __half2 v[8];
#pragma unroll
        for (int u = 0; u < 8; u++) {
            int i = j + 2 * u + half;
            s[u] = ssrc[beg + ((i < d) ? i : (d - 1))];
        }
#pragma unroll
        for (int u = 0; u < 8; u++) v[u] = Hv[(size_t)s[u] * 32 + cp];
#pragma unroll
        for (int u = 0; u < 8; u++) {
            if (j + 2 * u + half < d) {
                float2 f = __half22float2(v[u]);
                acc.x += f.x; acc.y += f.y;
            }
        }
    }
    acc.x += __shfl_xor(acc.x, 32, 64);
    acc.y += __shfl_xor(acc.y, 32, 64);
    if (half == 0) {
        float2 sf = __half22float2(Hv[(size_t)node * 32 + cp]);
        float2 b  = ((const float2*)bias)[cp];
        float ox = fmaf(di, acc.x + sf.x, b.x);
        float oy = fmaf(di, acc.y + sf.y, b.y);
        ((float2*)out)[(size_t)node * 32 + cp] = make_float2(ox, oy);
    }
}

// ---------------- launch ----------------

extern "C" void kernel_launch(void* const* d_in, const int* in_sizes, int n_in,
                              void* d_out, int out_size, void* d_ws, size_t ws_size,
                              hipStream_t stream) {
    const float* x  = (const float*)d_in[0];   // [N,128]
    const int*   ei = (const int*)d_in[1];     // [2,E]
    const float* W1 = (const float*)d_in[2];   // [128,128]
    const float* b1 = (const float*)d_in[3];   // [128]
    const float* W2 = (const float*)d_in[4];   // [128,64]
    const float* b2 = (const float*)d_in[5];   // [64]
    float* out = (float*)d_out;                // [N,64]

    const int* src = ei;
    const int* dst = ei + N_EDGES;

    char* p = (char*)d_ws;
    size_t off = 0;
    auto alloc = [&](size_t bytes) { void* q = p + off; off += (bytes + 255) & ~(size_t)255; return q; };
    float*  dinv    = (float*) alloc(N_NODES * 4);
    int*    deg     = (int*)   alloc(N_NODES * 4);
    int*    row_off = (int*)   alloc(N_NODES * 4);
    int*    cursor  = (int*)   alloc(N_NODES * 4);
    int*    parts   = (int*)   alloc(64 * 4);
    int*    ssrc    = (int*)   alloc(N_EDGES * 4);
    __bf16* w1hi    = (__bf16*)alloc(128 * 128 * 2);
    __bf16* w1lo    = (__bf16*)alloc(128 * 128 * 2);
    __bf16* w2hi    = (__bf16*)alloc(128 * 64 * 2);
    __bf16* w2lo    = (__bf16*)alloc(128 * 64 * 2);
    __half* hs1     = (__half*)alloc((size_t)N_NODES * 128 * 2);  // fp16 [N][128]
    __half* hs2     = (__half*)alloc((size_t)N_NODES * 64 * 2);   // fp16 [N][64]
    float*  x2      = (float*) alloc((size_t)N_NODES * 128 * 4);

    const int nb_scan = (N_NODES + 1023) / 1024;       // 49

    hipMemsetAsync(deg, 0, N_NODES * sizeof(int), stream);
    count_kernel<<<(N_EDGES + 255) / 256, 256, 0, stream>>>(dst, deg);
    scan_part_kernel<<<nb_scan, 256, 0, stream>>>(deg, parts);
    scan_blocks_kernel<<<1, 64, 0, stream>>>(parts, nb_scan);
    scan_final_kernel<<<nb_scan, 256, 0, stream>>>(deg, parts, row_off, cursor, dinv);
    fill_kernel<<<(N_EDGES + 255) / 256, 256, 0, stream>>>(src, dst, cursor, ssrc);

    wprep_kernel<128><<<8, 256, 0, stream>>>(W1, w1hi, w1lo);
    wprep_kernel<64> <<<4, 256, 0, stream>>>(W2, w2hi, w2lo);

    // layer 1: hs1 = fp16(dinv*(x@W1)); x2 = relu(dinv*(self+sum) + b1)
    gemm_mfma_kernel<128><<<(N_NODES + 63) / 64, 256, 0, stream>>>(x, w1hi, w1lo, dinv, hs1);
    aggregate128_kernel<true><<<(N_NODES * 64 + 255) / 256, 256, 0, stream>>>(
        hs1, row_off, deg, ssrc, dinv, b1, x2);

    // layer 2: hs2 = fp16(dinv*(x2@W2)); out = dinv*(self+sum) + b2
    gemm_mfma_kernel<64><<<(N_NODES + 63) / 64, 256, 0, stream>>>(x2, w2hi, w2lo, dinv, hs2);
    aggregate64_kernel<<<(N_NODES * 64 + 255) / 256, 256, 0, stream>>>(
        hs2, row_off, deg, ssrc, dinv, b2, out);
}

// Round 6
// 263.666 us; speedup vs baseline: 1.1733x; 1.0219x over previous
//
#include <hip/hip_runtime.h>
#include <hip/hip_fp16.h>

// GCN 2-layer: N=50000 nodes, E=800000 edges, 128 -> 128(relu) -> 64
// CSR-by-dst (dst-range-partitioned build: each 64B deg/cursor/ssrc line is
// owned by one of 8 range-groups -> no cross-XCD partial-line writebacks)
// -> h' = dinv*(x@W) via split-bf16 MFMA written as flat fp16 [N][C]
// -> wave-per-node gather aggregate (full fp16 row per wave-instr, 8 rows
// in flight), f32 accumulate, final dinv*sum + bias (+relu).
// R5 lesson: unpartitioned fill had 52MB WRITE (16x amplification) from
// 8 XCD L2s each holding the same ssrc line partially dirty.

#define N_NODES 50000
#define N_EDGES 800000
#define NPART   8
#define PART_SZ (N_NODES / NPART)      // 6250
#define EBLK    128                    // edge-slice blocks per range-group
#define EDGES_PER_BLK (N_EDGES / EBLK) // 6250

typedef __bf16 bf16x8 __attribute__((ext_vector_type(8)));
typedef float  f32x4  __attribute__((ext_vector_type(4)));

// ---------------- CSR build (range-partitioned) ----------------

__global__ __launch_bounds__(256) void count_part_kernel(
        const int* __restrict__ dst, int* __restrict__ deg) {
    int part = blockIdx.x & 7;
    int blk  = blockIdx.x >> 3;
    int lo = part * PART_SZ, hi = lo + PART_SZ;
    int e0 = blk * EDGES_PER_BLK;
    for (int e = e0 + threadIdx.x; e < e0 + EDGES_PER_BLK; e += 256) {
        int d = dst[e];
        if (d >= lo && d < hi) atomicAdd(&deg[d], 1);
    }
}

__global__ __launch_bounds__(256) void fill_part_kernel(
        const int* __restrict__ src, const int* __restrict__ dst,
        int* __restrict__ cursor, int* __restrict__ ssrc) {
    int part = blockIdx.x & 7;
    int blk  = blockIdx.x >> 3;
    int lo = part * PART_SZ, hi = lo + PART_SZ;
    int e0 = blk * EDGES_PER_BLK;
    for (int e = e0 + threadIdx.x; e < e0 + EDGES_PER_BLK; e += 256) {
        int d = dst[e];
        if (d >= lo && d < hi) {
            int p = atomicAdd(&cursor[d], 1);
            ssrc[p] = src[e];
        }
    }
}

// ---------------- scans ----------------

__global__ void scan_part_kernel(const int* __restrict__ deg, int* __restrict__ partials) {
    __shared__ int red[256];
    int tid = threadIdx.x;
    int base = blockIdx.x * 1024 + tid * 4;
    int s = 0;
#pragma unroll
    for (int i = 0; i < 4; i++) { int idx = base + i; if (idx < N_NODES) s += deg[idx]; }
    red[tid] = s; __syncthreads();
    for (int off = 128; off > 0; off >>= 1) {
        if (tid < off) red[tid] += red[tid + off];
        __syncthreads();
    }
    if (tid == 0) partials[blockIdx.x] = red[0];
}

__global__ void scan_blocks_kernel(int* partials, int nb) {
    int tid = threadIdx.x;            // 64 threads, one wave
    int orig = (tid < nb) ? partials[tid] : 0;
    int v = orig;
    for (int off = 1; off < 64; off <<= 1) {
        int t = __shfl_up(v, off, 64);
        if (tid >= off) v += t;
    }
    if (tid < nb) partials[tid] = v - orig;   // exclusive
}

__global__ void scan_final_kernel(const int* __restrict__ deg, const int* __restrict__ poff,
                                  int* __restrict__ row_off, int* __restrict__ cursor,
                                  float* __restrict__ dinv) {
    __shared__ int sc[256];
    int tid = threadIdx.x;
    int base = blockIdx.x * 1024 + tid * 4;
    int v[4]; int s = 0;
#pragma unroll
    for (int i = 0; i < 4; i++) { int idx = base + i; v[i] = (idx < N_NODES) ? deg[idx] : 0; s += v[i]; }
    sc[tid] = s; __syncthreads();
    for (int off = 1; off < 256; off <<= 1) {
        int t = (tid >= off) ? sc[tid - off] : 0;
        __syncthreads();
        sc[tid] += t;
        __syncthreads();
    }
    int run = sc[tid] - s + poff[blockIdx.x];
#pragma unroll
    for (int i = 0; i < 4; i++) {
        int idx = base + i;
        if (idx < N_NODES) {
            row_off[idx] = run;
            cursor[idx]  = run;
            dinv[idx]    = rsqrtf((float)(v[i] + 1));   // +1 self-loop
            run += v[i];
        }
    }
}

// ---------------- W prep: f32 [K=128][N] -> hi/lo bf16 B-fragments ----------------
template<int N>
__global__ void wprep_kernel(const float* __restrict__ W,
                             __bf16* __restrict__ hi, __bf16* __restrict__ lo) {
    int idx = blockIdx.x * 256 + threadIdx.x;     // total (N/16)*4*64
    if (idx >= (N / 16) * 4 * 64) return;
    int l = idx & 63;
    int s = (idx >> 6) & 3;
    int c = idx >> 8;
    int n = c * 16 + (l & 15);
    int k0 = s * 32 + (l >> 4) * 8;
#pragma unroll
    for (int j = 0; j < 8; j++) {
        float w = W[(k0 + j) * N + n];
        __bf16 h = (__bf16)w;
        hi[idx * 8 + j] = h;
        lo[idx * 8 + j] = (__bf16)(w - (float)h);
    }
}

// ---------------- GEMM: hs[row][OUTC] = fp16( dinv[row] * (X @ W)[row] ) ----------
template<int OUTC>
__global__ __launch_bounds__(256) void gemm_mfma_kernel(
        const float* __restrict__ X, const __bf16* __restrict__ Whi,
        const __bf16* __restrict__ Wlo, const float* __restrict__ dinv,
        __half* __restrict__ hs) {
    constexpr int NC = OUTC / 16;
    int tid = threadIdx.x;
    int w = tid >> 6, lane = tid & 63;
    int q = lane >> 4, lr = lane & 15;
    int rb = blockIdx.x * 64 + w * 16;
    int row = rb + lr;
    int rowc = (row < N_NODES) ? row : (N_NODES - 1);

    f32x4 acc[NC];
#pragma unroll
    for (int c = 0; c < NC; c++) acc[c] = (f32x4){0.f, 0.f, 0.f, 0.f};

#pragma unroll
    for (int s = 0; s < 4; s++) {
        const float* xp = X + (size_t)rowc * 128 + s * 32 + q * 8;
        float4 x0 = *(const float4*)xp;
        float4 x1 = *(const float4*)(xp + 4);
        float xv[8] = {x0.x, x0.y, x0.z, x0.w, x1.x, x1.y, x1.z, x1.w};
        bf16x8 a_hi, a_lo;
#pragma unroll
        for (int j = 0; j < 8; j++) {
            __bf16 h = (__bf16)xv[j];
            a_hi[j] = h;
            a_lo[j] = (__bf16)(xv[j] - (float)h);
        }
#pragma unroll
        for (int c = 0; c < NC; c++) {
            size_t fo = (size_t)((c * 4 + s) * 64 + lane) * 8;
            bf16x8 bh = *(const bf16x8*)(Whi + fo);
            bf16x8 bl = *(const bf16x8*)(Wlo + fo);
            acc[c] = __builtin_amdgcn_mfma_f32_16x16x32_bf16(a_hi, bh, acc[c], 0, 0, 0);
            acc[c] = __builtin_amdgcn_mfma_f32_16x16x32_bf16(a_lo, bh, acc[c], 0, 0, 0);
            acc[c] = __builtin_amdgcn_mfma_f32_16x16x32_bf16(a_hi, bl, acc[c], 0, 0, 0);
        }
    }

    // C/D layout: col = c*16 + lr, row(within 16) = q*4 + r
#pragma unroll
    for (int r = 0; r < 4; r++) {
        int grow = rb + q * 4 + r;
        if (grow < N_NODES) {
            float sc = dinv[grow];
#pragma unroll
            for (int c = 0; c < NC; c++) {
                hs[(size_t)grow * OUTC + c * 16 + lr] = __float2half(acc[c][r] * sc);
            }
        }
    }
}

// ---------------- Aggregate CH=128: wave per node, half2/lane = full 256B row -------
template<bool RELU>
__global__ __launch_bounds__(256) void aggregate128_kernel(
        const __half* __restrict__ hs, const int* __restrict__ row_off,
        const int* __restrict__ deg, const int* __restrict__ ssrc,
        const float* __restrict__ dinv, const float* __restrict__ bias,
        float* __restrict__ out) {
    int node = (blockIdx.x * 256 + threadIdx.x) >> 6;
    int lane = threadIdx.x & 63;
    if (node >= N_NODES) return;
    int beg = row_off[node];
    int d   = deg[node];
    float di = dinv[node];
    const __half2* Hv = (const __half2*)hs;      // [N][64] half2
    float2 acc = __half22float2(Hv[(size_t)node * 64 + lane]);   // self-loop
    for (int j = 0; j < d; j += 8) {
        int s[8]; __half2 v[8];
#pragma unroll
        for (int u = 0; u < 8; u++) {
            int i = j + u;
            s[u] = ssrc[beg + ((i < d) ? i : (d - 1))];
        }
#pragma unroll
        for (int u = 0; u < 8; u++) v[u] = Hv[(size_t)s[u] * 64 + lane];
#pragma unroll
        for (int u = 0; u < 8; u++) {
            if (j + u < d) {
                float2 f = __half22float2(v[u]);
                acc.x += f.x; acc.y += f.y;
            }
        }
    }
    float2 b = ((const float2*)bias)[lane];
    float ox = fmaf(di, acc.x, b.x);
    float oy = fmaf(di, acc.y, b.y);
    if (RELU) { ox = fmaxf(ox, 0.f); oy = fmaxf(oy, 0.f); }
    ((float2*)out)[(size_t)node * 64 + lane] = make_float2(ox, oy);
}

// ---------------- Aggregate CH=64: wave per node, 2 edges per gather instr ----------
__global__ __launch_bounds__(256) void aggregate64_kernel(
        const __half* __restrict__ hs, const int* __restrict__ row_off,
        const int* __restrict__ deg, const int* __restrict__ ssrc,
        const float* __restrict__ dinv, const float* __restrict__ bias,
        float* __restrict__ out) {
    int node = (blockIdx.x * 256 + threadIdx.x) >> 6;
    int lane = threadIdx.x & 63;
    if (node >= N_NODES) return;
    int beg = row_off[node];
    int d   = deg[node];
    float di = dinv[node];
    int half = lane >> 5, cp = lane & 31;
    const __half2* Hv = (const __half2*)hs;      // [N][32] half2
    float2 acc = make_float2(0.f, 0.f);
    for (int j = 0; j < d; j += 16) {
        int s[8]; __half2 v[8];
#pragma unroll
        for (int u = 0; u < 8; u++) {
            int i = j + 2 * u + half;
            s[u] = ssrc[beg + ((i < d) ? i : (d - 1))];
        }
#pragma unroll
        for (int u = 0; u < 8; u++) v[u] = Hv[(size_t)s[u] * 32 + cp];
#pragma unroll
        for (int u = 0; u < 8; u++) {
            if (j + 2 * u + half < d) {
                float2 f = __half22float2(v[u]);
                acc.x += f.x; acc.y += f.y;
            }
        }
    }
    acc.x += __shfl_xor(acc.x, 32, 64);
    acc.y += __shfl_xor(acc.y, 32, 64);
    if (half == 0) {
        float2 sf = __half22float2(Hv[(size_t)node * 32 + cp]);
        float2 b  = ((const float2*)bias)[cp];
        float ox = fmaf(di, acc.x + sf.x, b.x);
        float oy = fmaf(di, acc.y + sf.y, b.y);
        ((float2*)out)[(size_t)node * 32 + cp] = make_float2(ox, oy);
    }
}

// ---------------- launch ----------------

extern "C" void kernel_launch(void* const* d_in, const int* in_sizes, int n_in,
                              void* d_out, int out_size, void* d_ws, size_t ws_size,
                              hipStream_t stream) {
    const float* x  = (const float*)d_in[0];   // [N,128]
    const int*   ei = (const int*)d_in[1];     // [2,E]
    const float* W1 = (const float*)d_in[2];   // [128,128]
    const float* b1 = (const float*)d_in[3];   // [128]
    const float* W2 = (const float*)d_in[4];   // [128,64]
    const float* b2 = (const float*)d_in[5];   // [64]
    float* out = (float*)d_out;                // [N,64]

    const int* src = ei;
    const int* dst = ei + N_EDGES;

    char* p = (char*)d_ws;
    size_t off = 0;
    auto alloc = [&](size_t bytes) { void* q = p + off; off += (bytes + 255) & ~(size_t)255; return q; };
    float*  dinv    = (float*) alloc(N_NODES * 4);
    int*    deg     = (int*)   alloc(N_NODES * 4);
    int*    row_off = (int*)   alloc(N_NODES * 4);
    int*    cursor  = (int*)   alloc(N_NODES * 4);
    int*    parts   = (int*)   alloc(64 * 4);
    int*    ssrc    = (int*)   alloc(N_EDGES * 4);
    __bf16* w1hi    = (__bf16*)alloc(128 * 128 * 2);
    __bf16* w1lo    = (__bf16*)alloc(128 * 128 * 2);
    __bf16* w2hi    = (__bf16*)alloc(128 * 64 * 2);
    __bf16* w2lo    = (__bf16*)alloc(128 * 64 * 2);
    __half* hs1     = (__half*)alloc((size_t)N_NODES * 128 * 2);  // fp16 [N][128]
    __half* hs2     = (__half*)alloc((size_t)N_NODES * 64 * 2);   // fp16 [N][64]
    float*  x2      = (float*) alloc((size_t)N_NODES * 128 * 4);

    const int nb_scan = (N_NODES + 1023) / 1024;       // 49

    hipMemsetAsync(deg, 0, N_NODES * sizeof(int), stream);
    count_part_kernel<<<NPART * EBLK, 256, 0, stream>>>(dst, deg);
    scan_part_kernel<<<nb_scan, 256, 0, stream>>>(deg, parts);
    scan_blocks_kernel<<<1, 64, 0, stream>>>(parts, nb_scan);
    scan_final_kernel<<<nb_scan, 256, 0, stream>>>(deg, parts, row_off, cursor, dinv);
    fill_part_kernel<<<NPART * EBLK, 256, 0, stream>>>(src, dst, cursor, ssrc);

    wprep_kernel<128><<<8, 256, 0, stream>>>(W1, w1hi, w1lo);
    wprep_kernel<64> <<<4, 256, 0, stream>>>(W2, w2hi, w2lo);

    // layer 1: hs1 = fp16(dinv*(x@W1)); x2 = relu(dinv*(self+sum) + b1)
    gemm_mfma_kernel<128><<<(N_NODES + 63) / 64, 256, 0, stream>>>(x, w1hi, w1lo, dinv, hs1);
    aggregate128_kernel<true><<<(N_NODES * 64 + 255) / 256, 256, 0, stream>>>(
        hs1, row_off, deg, ssrc, dinv, b1, x2);

    // layer 2: hs2 = fp16(dinv*(x2@W2)); out = dinv*(self+sum) + b2
    gemm_mfma_kernel<64><<<(N_NODES + 63) / 64, 256, 0, stream>>>(x2, w2hi, w2lo, dinv, hs2);
    aggregate64_kernel<<<(N_NODES * 64 + 255) / 256, 256, 0, stream>>>(
        hs2, row_off, deg, ssrc, dinv, b2, out);
}

// Round 7
// 210.488 us; speedup vs baseline: 1.4697x; 1.2526x over previous
//
#include <hip/hip_runtime.h>
#include <hip/hip_fp16.h>

// GCN 2-layer: N=50000 nodes, E=800000 edges, 128 -> 128(relu) -> 64
// CSR-by-dst via two-level binned counting sort (R6 rewrite):
//   bin_scatter: 1 edge pass, LDS-compact by bin(=dst>>7), bulk global
//                atomicAdd per (block,bin) (~77k atomics vs 800k), packed
//                (dst<<16|src) into fixed-cap bin array (single-writer regions)
//   bin_count:   per-bin LDS histogram -> deg (no global atomics, no memset)
//   scans     -> row_off, dinv
//   bin_fill:    per-bin LDS cursors -> ssrc (LDS atomics, single-writer 8KB)
// then h' = dinv*(x@W) via split-bf16 MFMA -> flat fp16 [N][C] ->
// wave-per-node gather aggregate (8 rows in flight) -> dinv*sum+bias(+relu).
// R6 lesson: per-edge L2 atomic-return + scattered 4B stores = latency wall;
// range partitioning didn't fix it (45.9us, VALUBusy 2.7%).

#define N_NODES 50000
#define N_EDGES 800000
#define BINW    128
#define NBIN    391                    // ceil(50000/128)
#define CAP     2560                   // mean 2046, ~11 sigma margin
#define B_CHUNK 4096
#define NB_SCAT ((N_EDGES + B_CHUNK - 1) / B_CHUNK)   // 196

typedef __bf16 bf16x8 __attribute__((ext_vector_type(8)));
typedef float  f32x4  __attribute__((ext_vector_type(4)));

// ---------------- CSR build: binned counting sort ----------------

__global__ __launch_bounds__(256) void bin_scatter_kernel(
        const int* __restrict__ src, const int* __restrict__ dst,
        int* __restrict__ gcur, unsigned* __restrict__ ebin) {
    __shared__ int cnt[512];          // per-bin counts (NBIN padded to 512)
    __shared__ int boff[512];         // bin start in staging
    __shared__ int bcur[512];
    __shared__ int gbase[512];
    __shared__ unsigned stage[B_CHUNK];
    __shared__ int ex[256];
    int tid = threadIdx.x;
    int e0 = blockIdx.x * B_CHUNK;

    cnt[tid] = 0; cnt[tid + 256] = 0;
    __syncthreads();

    unsigned key[16]; int bins[16];
#pragma unroll
    for (int i = 0; i < 16; i++) {
        int e = e0 + tid + i * 256;               // coalesced
        if (e < N_EDGES) {
            int d = dst[e], s = src[e];
            key[i]  = ((unsigned)d << 16) | (unsigned)s;
            bins[i] = d >> 7;
            atomicAdd(&cnt[bins[i]], 1);
        } else bins[i] = -1;
    }
    __syncthreads();

    // exclusive scan of 512 bin counts with 256 threads (2 bins each)
    int a = cnt[2 * tid], b = cnt[2 * tid + 1];
    ex[tid] = a + b;
    __syncthreads();
    for (int off = 1; off < 256; off <<= 1) {
        int t = (tid >= off) ? ex[tid - off] : 0;
        __syncthreads();
        ex[tid] += t;
        __syncthreads();
    }
    int myex = ex[tid] - (a + b);
    boff[2 * tid] = myex;     boff[2 * tid + 1] = myex + a;
    bcur[2 * tid] = myex;     bcur[2 * tid + 1] = myex + a;
    __syncthreads();

    // compact into bin-contiguous staging
#pragma unroll
    for (int i = 0; i < 16; i++) {
        if (bins[i] >= 0) {
            int p = atomicAdd(&bcur[bins[i]], 1);
            stage[p] = key[i];
        }
    }

    // bulk-reserve global bin space (one atomic per non-empty (block,bin))
    __syncthreads();
    for (int b2 = tid; b2 < NBIN; b2 += 256) {
        int c = cnt[b2];
        gbase[b2] = (c > 0) ? atomicAdd(&gcur[b2], c) : 0;
    }
    __syncthreads();

    // write out: element i of staging -> ebin[bin*CAP + gbase[bin] + (i - boff[bin])]
    int total = N_EDGES - e0; if (total > B_CHUNK) total = B_CHUNK;
    for (int i = tid; i < total; i += 256) {
        unsigned k = stage[i];
        int bin = (int)(k >> 23);                 // dst>>7
        int idx = gbase[bin] + (i - boff[bin]);
        if (idx < CAP) ebin[(size_t)bin * CAP + idx] = k;  // guard (11-sigma)
    }
}

__global__ __launch_bounds__(256) void bin_count_kernel(
        const unsigned* __restrict__ ebin, const int* __restrict__ gcur,
        int* __restrict__ deg) {
    __shared__ int dl[BINW];
    int bin = blockIdx.x, tid = threadIdx.x;
    if (tid < BINW) dl[tid] = 0;
    __syncthreads();
    int cnt = gcur[bin]; if (cnt > CAP) cnt = CAP;
    const unsigned* eb = ebin + (size_t)bin * CAP;
    for (int i = tid; i < cnt; i += 256)
        atomicAdd(&dl[(eb[i] >> 16) & 127], 1);
    __syncthreads();
    int node = bin * BINW + tid;
    if (tid < BINW && node < N_NODES) deg[node] = dl[tid];
}

__global__ __launch_bounds__(256) void bin_fill_kernel(
        const unsigned* __restrict__ ebin, const int* __restrict__ gcur,
        const int* __restrict__ row_off, int* __restrict__ ssrc) {
    __shared__ int cur[BINW];
    int bin = blockIdx.x, tid = threadIdx.x;
    int node = bin * BINW + tid;
    if (tid < BINW) cur[tid] = (node < N_NODES) ? row_off[node] : 0;
    __syncthreads();
    int cnt = gcur[bin]; if (cnt > CAP) cnt = CAP;
    const unsigned* eb = ebin + (size_t)bin * CAP;
    for (int i = tid; i < cnt; i += 256) {
        unsigned k = eb[i];
        int p = atomicAdd(&cur[(k >> 16) & 127], 1);
        ssrc[p] = (int)(k & 0xFFFFu);
    }
}

// ---------------- scans ----------------

__global__ void scan_part_kernel(const int* __restrict__ deg, int* __restrict__ partials) {
    __shared__ int red[256];
    int tid = threadIdx.x;
    int base = blockIdx.x * 1024 + tid * 4;
    int s = 0;
#pragma unroll
    for (int i = 0; i < 4; i++) { int idx = base + i; if (idx < N_NODES) s += deg[idx]; }
    red[tid] = s; __syncthreads();
    for (int off = 128; off > 0; off >>= 1) {
        if (tid < off) red[tid] += red[tid + off];
        __syncthreads();
    }
    if (tid == 0) partials[blockIdx.x] = red[0];
}

__global__ void scan_blocks_kernel(int* partials, int nb) {
    int tid = threadIdx.x;            // 64 threads, one wave
    int orig = (tid < nb) ? partials[tid] : 0;
    int v = orig;
    for (int off = 1; off < 64; off <<= 1) {
        int t = __shfl_up(v, off, 64);
        if (tid >= off) v += t;
    }
    if (tid < nb) partials[tid] = v - orig;   // exclusive
}

__global__ void scan_final_kernel(const int* __restrict__ deg, const int* __restrict__ poff,
                                  int* __restrict__ row_off, float* __restrict__ dinv) {
    __shared__ int sc[256];
    int tid = threadIdx.x;
    int base = blockIdx.x * 1024 + tid * 4;
    int v[4]; int s = 0;
#pragma unroll
    for (int i = 0; i < 4; i++) { int idx = base + i; v[i] = (idx < N_NODES) ? deg[idx] : 0; s += v[i]; }
    sc[tid] = s; __syncthreads();
    for (int off = 1; off < 256; off <<= 1) {
        int t = (tid >= off) ? sc[tid - off] : 0;
        __syncthreads();
        sc[tid] += t;
        __syncthreads();
    }
    int run = sc[tid] - s + poff[blockIdx.x];
#pragma unroll
    for (int i = 0; i < 4; i++) {
        int idx = base + i;
        if (idx < N_NODES) {
            row_off[idx] = run;
            dinv[idx]    = rsqrtf((float)(v[i] + 1));   // +1 self-loop
            run += v[i];
        }
    }
}

// ---------------- W prep: f32 [K=128][N] -> hi/lo bf16 B-fragments ----------------
template<int N>
__global__ void wprep_kernel(const float* __restrict__ W,
                             __bf16* __restrict__ hi, __bf16* __restrict__ lo) {
    int idx = blockIdx.x * 256 + threadIdx.x;     // total (N/16)*4*64
    if (idx >= (N / 16) * 4 * 64) return;
    int l = idx & 63;
    int s = (idx >> 6) & 3;
    int c = idx >> 8;
    int n = c * 16 + (l & 15);
    int k0 = s * 32 + (l >> 4) * 8;
#pragma unroll
    for (int j = 0; j < 8; j++) {
        float w = W[(k0 + j) * N + n];
        __bf16 h = (__bf16)w;
        hi[idx * 8 + j] = h;
        lo[idx * 8 + j] = (__bf16)(w - (float)h);
    }
}

// ---------------- GEMM: hs[row][OUTC] = fp16( dinv[row] * (X @ W)[row] ) ----------
template<int OUTC>
__global__ __launch_bounds__(256) void gemm_mfma_kernel(
        const float* __restrict__ X, const __bf16* __restrict__ Whi,
        const __bf16* __restrict__ Wlo, const float* __restrict__ dinv,
        __half* __restrict__ hs) {
    constexpr int NC = OUTC / 16;
    int tid = threadIdx.x;
    int w = tid >> 6, lane = tid & 63;
    int q = lane >> 4, lr = lane & 15;
    int rb = blockIdx.x * 64 + w * 16;
    int row = rb + lr;
    int rowc = (row < N_NODES) ? row : (N_NODES - 1);

    f32x4 acc[NC];
#pragma unroll
    for (int c = 0; c < NC; c++) acc[c] = (f32x4){0.f, 0.f, 0.f, 0.f};

#pragma unroll
    for (int s = 0; s < 4; s++) {
        const float* xp = X + (size_t)rowc * 128 + s * 32 + q * 8;
        float4 x0 = *(const float4*)xp;
        float4 x1 = *(const float4*)(xp + 4);
        float xv[8] = {x0.x, x0.y, x0.z, x0.w, x1.x, x1.y, x1.z, x1.w};
        bf16x8 a_hi, a_lo;
#pragma unroll
        for (int j = 0; j < 8; j++) {
            __bf16 h = (__bf16)xv[j];
            a_hi[j] = h;
            a_lo[j] = (__bf16)(xv[j] - (float)h);
        }
#pragma unroll
        for (int c = 0; c < NC; c++) {
            size_t fo = (size_t)((c * 4 + s) * 64 + lane) * 8;
            bf16x8 bh = *(const bf16x8*)(Whi + fo);
            bf16x8 bl = *(const bf16x8*)(Wlo + fo);
            acc[c] = __builtin_amdgcn_mfma_f32_16x16x32_bf16(a_hi, bh, acc[c], 0, 0, 0);
            acc[c] = __builtin_amdgcn_mfma_f32_16x16x32_bf16(a_lo, bh, acc[c], 0, 0, 0);
            acc[c] = __builtin_amdgcn_mfma_f32_16x16x32_bf16(a_hi, bl, acc[c], 0, 0, 0);
        }
    }

    // C/D layout: col = c*16 + lr, row(within 16) = q*4 + r
#pragma unroll
    for (int r = 0; r < 4; r++) {
        int grow = rb + q * 4 + r;
        if (grow < N_NODES) {
            float sc = dinv[grow];
#pragma unroll
            for (int c = 0; c < NC; c++) {
                hs[(size_t)grow * OUTC + c * 16 + lr] = __float2half(acc[c][r] * sc);
            }
        }
    }
}

// ---------------- Aggregate CH=128: wave per node, half2/lane = full 256B row -------
template<bool RELU>
__global__ __launch_bounds__(256) void aggregate128_kernel(
        const __half* __restrict__ hs, const int* __restrict__ row_off,
        const int* __restrict__ deg, const int* __restrict__ ssrc,
        const float* __restrict__ dinv, const float* __restrict__ bias,
        float* __restrict__ out) {
    int node = (blockIdx.x * 256 + threadIdx.x) >> 6;
    int lane = threadIdx.x & 63;
    if (node >= N_NODES) return;
    int beg = row_off[node];
    int d   = deg[node];
    float di = dinv[node];
    const __half2* Hv = (const __half2*)hs;      // [N][64] half2
    float2 acc = __half22float2(Hv[(size_t)node * 64 + lane]);   // self-loop
    for (int j = 0; j < d; j += 8) {
        int s[8]; __half2 v[8];
#pragma unroll
        for (int u = 0; u < 8; u++) {
            int i = j + u;
            s[u] = ssrc[beg + ((i < d) ? i : (d - 1))];
        }
#pragma unroll
        for (int u = 0; u < 8; u++) v[u] = Hv[(size_t)s[u] * 64 + lane];
#pragma unroll
        for (int u = 0; u < 8; u++) {
            if (j + u < d) {
                float2 f = __half22float2(v[u]);
                acc.x += f.x; acc.y += f.y;
            }
        }
    }
    float2 b = ((const float2*)bias)[lane];
    float ox = fmaf(di, acc.x, b.x);
    float oy = fmaf(di, acc.y, b.y);
    if (RELU) { ox = fmaxf(ox, 0.f); oy = fmaxf(oy, 0.f); }
    ((float2*)out)[(size_t)node * 64 + lane] = make_float2(ox, oy);
}

// ---------------- Aggregate CH=64: wave per node, 2 edges per gather instr ----------
__global__ __launch_bounds__(256) void aggregate64_kernel(
        const __half* __restrict__ hs, const int* __restrict__ row_off,
        const int* __restrict__ deg, const int* __restrict__ ssrc,
        const float* __restrict__ dinv, const float* __restrict__ bias,
        float* __restrict__ out) {
    int node = (blockIdx.x * 256 + threadIdx.x) >> 6;
    int lane = threadIdx.x & 63;
    if (node >= N_NODES) return;
    int beg = row_off[node];
    int d   = deg[node];
    float di = dinv[node];
    int half = lane >> 5, cp = lane & 31;
    const __half2* Hv = (const __half2*)hs;      // [N][32] half2
    float2 acc = make_float2(0.f, 0.f);
    for (int j = 0; j < d; j += 16) {
        int s[8]; __half2 v[8];
#pragma unroll
        for (int u = 0; u < 8; u++) {
            int i = j + 2 * u + half;
            s[u] = ssrc[beg + ((i < d) ? i : (d - 1))];
        }
#pragma unroll
        for (int u = 0; u < 8; u++) v[u] = Hv[(size_t)s[u] * 32 + cp];
#pragma unroll
        for (int u = 0; u < 8; u++) {
            if (j + 2 * u + half < d) {
                float2 f = __half22float2(v[u]);
                acc.x += f.x; acc.y += f.y;
            }
        }
    }
    acc.x += __shfl_xor(acc.x, 32, 64);
    acc.y += __shfl_xor(acc.y, 32, 64);
    if (half == 0) {
        float2 sf = __half22float2(Hv[(size_t)node * 32 + cp]);
        float2 b  = ((const float2*)bias)[cp];
        float ox = fmaf(di, acc.x + sf.x, b.x);
        float oy = fmaf(di, acc.y + sf.y, b.y);
        ((float2*)out)[(size_t)node * 32 + cp] = make_float2(ox, oy);
    }
}

// ---------------- launch ----------------

extern "C" void kernel_launch(void* const* d_in, const int* in_sizes, int n_in,
                              void* d_out, int out_size, void* d_ws, size_t ws_size,
                              hipStream_t stream) {
    const float* x  = (const float*)d_in[0];   // [N,128]
    const int*   ei = (const int*)d_in[1];     // [2,E]
    const float* W1 = (const float*)d_in[2];   // [128,128]
    const float* b1 = (const float*)d_in[3];   // [128]
    const float* W2 = (const float*)d_in[4];   // [128,64]
    const float* b2 = (const float*)d_in[5];   // [64]
    float* out = (float*)d_out;                // [N,64]

    const int* src = ei;
    const int* dst = ei + N_EDGES;

    char* p = (char*)d_ws;
    size_t off = 0;
    auto alloc = [&](size_t bytes) { void* q = p + off; off += (bytes + 255) & ~(size_t)255; return q; };
    float*    dinv    = (float*)   alloc(N_NODES * 4);
    int*      deg     = (int*)     alloc(N_NODES * 4);
    int*      row_off = (int*)     alloc(N_NODES * 4);
    int*      gcur    = (int*)     alloc(NBIN * 4);
    int*      parts   = (int*)     alloc(64 * 4);
    int*      ssrc    = (int*)     alloc(N_EDGES * 4);
    unsigned* ebin    = (unsigned*)alloc((size_t)NBIN * CAP * 4);   // 4.0 MB
    __bf16*   w1hi    = (__bf16*)  alloc(128 * 128 * 2);
    __bf16*   w1lo    = (__bf16*)  alloc(128 * 128 * 2);
    __bf16*   w2hi    = (__bf16*)  alloc(128 * 64 * 2);
    __bf16*   w2lo    = (__bf16*)  alloc(128 * 64 * 2);
    __half*   hs1     = (__half*)  alloc((size_t)N_NODES * 128 * 2);
    __half*   hs2     = (__half*)  alloc((size_t)N_NODES * 64 * 2);
    float*    x2      = (float*)   alloc((size_t)N_NODES * 128 * 4);

    const int nb_scan = (N_NODES + 1023) / 1024;       // 49

    hipMemsetAsync(gcur, 0, NBIN * sizeof(int), stream);
    bin_scatter_kernel<<<NB_SCAT, 256, 0, stream>>>(src, dst, gcur, ebin);
    bin_count_kernel<<<NBIN, 256, 0, stream>>>(ebin, gcur, deg);
    scan_part_kernel<<<nb_scan, 256, 0, stream>>>(deg, parts);
    scan_blocks_kernel<<<1, 64, 0, stream>>>(parts, nb_scan);
    scan_final_kernel<<<nb_scan, 256, 0, stream>>>(deg, parts, row_off, dinv);
    bin_fill_kernel<<<NBIN, 256, 0, stream>>>(ebin, gcur, row_off, ssrc);

    wprep_kernel<128><<<8, 256, 0, stream>>>(W1, w1hi, w1lo);
    wprep_kernel<64> <<<4, 256, 0, stream>>>(W2, w2hi, w2lo);

    // layer 1: hs1 = fp16(dinv*(x@W1)); x2 = relu(dinv*(self+sum) + b1)
    gemm_mfma_kernel<128><<<(N_NODES + 63) / 64, 256, 0, stream>>>(x, w1hi, w1lo, dinv, hs1);
    aggregate128_kernel<true><<<(N_NODES * 64 + 255) / 256, 256, 0, stream>>>(
        hs1, row_off, deg, ssrc, dinv, b1, x2);

    // layer 2: hs2 = fp16(dinv*(x2@W2)); out = dinv*(self+sum) + b2
    gemm_mfma_kernel<64><<<(N_NODES + 63) / 64, 256, 0, stream>>>(x2, w2hi, w2lo, dinv, hs2);
    aggregate64_kernel<<<(N_NODES * 64 + 255) / 256, 256, 0, stream>>>(
        hs2, row_off, deg, ssrc, dinv, b2, out);
}

// Round 8
// 207.988 us; speedup vs baseline: 1.4873x; 1.0120x over previous
//
#include <hip/hip_runtime.h>
#include <hip/hip_fp16.h>

// GCN 2-layer: N=50000 nodes, E=800000 edges, 128 -> 128(relu) -> 64
// CSR-by-dst via binned counting sort (R7) -> h' = dinv*(x@W) via split-bf16
// MFMA -> flat fp16 [N][C] -> wave-per-node gather aggregate with 8B/lane
// dwordx2 gathers: 2 rows/instr (CH=128), 4 rows/instr (CH=64), 16/32 edges
// in flight -> fold via shfl_xor -> dinv*sum + bias (+relu), float4 stores.
// R7 lesson: 4B/lane gathers left agg128 at 43us/2.6TB/s (issue-bound);
// doubling per-instr payload is the MLP lever that doesn't split waves (R4).

#define N_NODES 50000
#define N_EDGES 800000
#define BINW    128
#define NBIN    391                    // ceil(50000/128)
#define CAP     2560                   // mean 2046, ~11 sigma margin
#define B_CHUNK 4096
#define NB_SCAT ((N_EDGES + B_CHUNK - 1) / B_CHUNK)   // 196

typedef __bf16 bf16x8 __attribute__((ext_vector_type(8)));
typedef float  f32x4  __attribute__((ext_vector_type(4)));

// ---------------- CSR build: binned counting sort ----------------

__global__ __launch_bounds__(256) void bin_scatter_kernel(
        const int* __restrict__ src, const int* __restrict__ dst,
        int* __restrict__ gcur, unsigned* __restrict__ ebin) {
    __shared__ int cnt[512];          // per-bin counts (NBIN padded to 512)
    __shared__ int boff[512];         // bin start in staging
    __shared__ int bcur[512];
    __shared__ int gbase[512];
    __shared__ unsigned stage[B_CHUNK];
    __shared__ int ex[256];
    int tid = threadIdx.x;
    int e0 = blockIdx.x * B_CHUNK;

    cnt[tid] = 0; cnt[tid + 256] = 0;
    __syncthreads();

    unsigned key[16]; int bins[16];
#pragma unroll
    for (int i = 0; i < 16; i++) {
        int e = e0 + tid + i * 256;               // coalesced
        if (e < N_EDGES) {
            int d = dst[e], s = src[e];
            key[i]  = ((unsigned)d << 16) | (unsigned)s;
            bins[i] = d >> 7;
            atomicAdd(&cnt[bins[i]], 1);
        } else bins[i] = -1;
    }
    __syncthreads();

    // exclusive scan of 512 bin counts with 256 threads (2 bins each)
    int a = cnt[2 * tid], b = cnt[2 * tid + 1];
    ex[tid] = a + b;
    __syncthreads();
    for (int off = 1; off < 256; off <<= 1) {
        int t = (tid >= off) ? ex[tid - off] : 0;
        __syncthreads();
        ex[tid] += t;
        __syncthreads();
    }
    int myex = ex[tid] - (a + b);
    boff[2 * tid] = myex;     boff[2 * tid + 1] = myex + a;
    bcur[2 * tid] = myex;     bcur[2 * tid + 1] = myex + a;
    __syncthreads();

    // compact into bin-contiguous staging
#pragma unroll
    for (int i = 0; i < 16; i++) {
        if (bins[i] >= 0) {
            int p = atomicAdd(&bcur[bins[i]], 1);
            stage[p] = key[i];
        }
    }

    // bulk-reserve global bin space (one atomic per non-empty (block,bin))
    __syncthreads();
    for (int b2 = tid; b2 < NBIN; b2 += 256) {
        int c = cnt[b2];
        gbase[b2] = (c > 0) ? atomicAdd(&gcur[b2], c) : 0;
    }
    __syncthreads();

    // write out: element i of staging -> ebin[bin*CAP + gbase[bin] + (i - boff[bin])]
    int total = N_EDGES - e0; if (total > B_CHUNK) total = B_CHUNK;
    for (int i = tid; i < total; i += 256) {
        unsigned k = stage[i];
        int bin = (int)(k >> 23);                 // dst>>7
        int idx = gbase[bin] + (i - boff[bin]);
        if (idx < CAP) ebin[(size_t)bin * CAP + idx] = k;  // guard (11-sigma)
    }
}

__global__ __launch_bounds__(256) void bin_count_kernel(
        const unsigned* __restrict__ ebin, const int* __restrict__ gcur,
        int* __restrict__ deg) {
    __shared__ int dl[BINW];
    int bin = blockIdx.x, tid = threadIdx.x;
    if (tid < BINW) dl[tid] = 0;
    __syncthreads();
    int cnt = gcur[bin]; if (cnt > CAP) cnt = CAP;
    const unsigned* eb = ebin + (size_t)bin * CAP;
    for (int i = tid; i < cnt; i += 256)
        atomicAdd(&dl[(eb[i] >> 16) & 127], 1);
    __syncthreads();
    int node = bin * BINW + tid;
    if (tid < BINW && node < N_NODES) deg[node] = dl[tid];
}

__global__ __launch_bounds__(256) void bin_fill_kernel(
        const unsigned* __restrict__ ebin, const int* __restrict__ gcur,
        const int* __restrict__ row_off, int* __restrict__ ssrc) {
    __shared__ int cur[BINW];
    int bin = blockIdx.x, tid = threadIdx.x;
    int node = bin * BINW + tid;
    if (tid < BINW) cur[tid] = (node < N_NODES) ? row_off[node] : 0;
    __syncthreads();
    int cnt = gcur[bin]; if (cnt > CAP) cnt = CAP;
    const unsigned* eb = ebin + (size_t)bin * CAP;
    for (int i = tid; i < cnt; i += 256) {
        unsigned k = eb[i];
        int p = atomicAdd(&cur[(k >> 16) & 127], 1);
        ssrc[p] = (int)(k & 0xFFFFu);
    }
}

// ---------------- scans ----------------

__global__ void scan_part_kernel(const int* __restrict__ deg, int* __restrict__ partials) {
    __shared__ int red[256];
    int tid = threadIdx.x;
    int base = blockIdx.x * 1024 + tid * 4;
    int s = 0;
#pragma unroll
    for (int i = 0; i < 4; i++) { int idx = base + i; if (idx < N_NODES) s += deg[idx]; }
    red[tid] = s; __syncthreads();
    for (int off = 128; off > 0; off >>= 1) {
        if (tid < off) red[tid] += red[tid + off];
        __syncthreads();
    }
    if (tid == 0) partials[blockIdx.x] = red[0];
}

__global__ void scan_blocks_kernel(int* partials, int nb) {
    int tid = threadIdx.x;            // 64 threads, one wave
    int orig = (tid < nb) ? partials[tid] : 0;
    int v = orig;
    for (int off = 1; off < 64; off <<= 1) {
        int t = __shfl_up(v, off, 64);
        if (tid >= off) v += t;
    }
    if (tid < nb) partials[tid] = v - orig;   // exclusive
}

__global__ void scan_final_kernel(const int* __restrict__ deg, const int* __restrict__ poff,
                                  int* __restrict__ row_off, float* __restrict__ dinv) {
    __shared__ int sc[256];
    int tid = threadIdx.x;
    int base = blockIdx.x * 1024 + tid * 4;
    int v[4]; int s = 0;
#pragma unroll
    for (int i = 0; i < 4; i++) { int idx = base + i; v[i] = (idx < N_NODES) ? deg[idx] : 0; s += v[i]; }
    sc[tid] = s; __syncthreads();
    for (int off = 1; off < 256; off <<= 1) {
        int t = (tid >= off) ? sc[tid - off] : 0;
        __syncthreads();
        sc[tid] += t;
        __syncthreads();
    }
    int run = sc[tid] - s + poff[blockIdx.x];
#pragma unroll
    for (int i = 0; i < 4; i++) {
        int idx = base + i;
        if (idx < N_NODES) {
            row_off[idx] = run;
            dinv[idx]    = rsqrtf((float)(v[i] + 1));   // +1 self-loop
            run += v[i];
        }
    }
}

// ---------------- W prep: f32 [K=128][N] -> hi/lo bf16 B-fragments ----------------
template<int N>
__global__ void wprep_kernel(const float* __restrict__ W,
                             __bf16* __restrict__ hi, __bf16* __restrict__ lo) {
    int idx = blockIdx.x * 256 + threadIdx.x;     // total (N/16)*4*64
    if (idx >= (N / 16) * 4 * 64) return;
    int l = idx & 63;
    int s = (idx >> 6) & 3;
    int c = idx >> 8;
    int n = c * 16 + (l & 15);
    int k0 = s * 32 + (l >> 4) * 8;
#pragma unroll
    for (int j = 0; j < 8; j++) {
        float w = W[(k0 + j) * N + n];
        __bf16 h = (__bf16)w;
        hi[idx * 8 + j] = h;
        lo[idx * 8 + j] = (__bf16)(w - (float)h);
    }
}

// ---------------- GEMM: hs[row][OUTC] = fp16( dinv[row] * (X @ W)[row] ) ----------
template<int OUTC>
__global__ __launch_bounds__(256) void gemm_mfma_kernel(
        const float* __restrict__ X, const __bf16* __restrict__ Whi,
        const __bf16* __restrict__ Wlo, const float* __restrict__ dinv,
        __half* __restrict__ hs) {
    constexpr int NC = OUTC / 16;
    int tid = threadIdx.x;
    int w = tid >> 6, lane = tid & 63;
    int q = lane >> 4, lr = lane & 15;
    int rb = blockIdx.x * 64 + w * 16;
    int row = rb + lr;
    int rowc = (row < N_NODES) ? row : (N_NODES - 1);

    f32x4 acc[NC];
#pragma unroll
    for (int c = 0; c < NC; c++) acc[c] = (f32x4){0.f, 0.f, 0.f, 0.f};

#pragma unroll
    for (int s = 0; s < 4; s++) {
        const float* xp = X + (size_t)rowc * 128 + s * 32 + q * 8;
        float4 x0 = *(const float4*)xp;
        float4 x1 = *(const float4*)(xp + 4);
        float xv[8] = {x0.x, x0.y, x0.z, x0.w, x1.x, x1.y, x1.z, x1.w};
        bf16x8 a_hi, a_lo;
#pragma unroll
        for (int j = 0; j < 8; j++) {
            __bf16 h = (__bf16)xv[j];
            a_hi[j] = h;
            a_lo[j] = (__bf16)(xv[j] - (float)h);
        }
#pragma unroll
        for (int c = 0; c < NC; c++) {
            size_t fo = (size_t)((c * 4 + s) * 64 + lane) * 8;
            bf16x8 bh = *(const bf16x8*)(Whi + fo);
            bf16x8 bl = *(const bf16x8*)(Wlo + fo);
            acc[c] = __builtin_amdgcn_mfma_f32_16x16x32_bf16(a_hi, bh, acc[c], 0, 0, 0);
            acc[c] = __builtin_amdgcn_mfma_f32_16x16x32_bf16(a_lo, bh, acc[c], 0, 0, 0);
            acc[c] = __builtin_amdgcn_mfma_f32_16x16x32_bf16(a_hi, bl, acc[c], 0, 0, 0);
        }
    }

    // C/D layout: col = c*16 + lr, row(within 16) = q*4 + r
#pragma unroll
    for (int r = 0; r < 4; r++) {
        int grow = rb + q * 4 + r;
        if (grow < N_NODES) {
            float sc = dinv[grow];
#pragma unroll
            for (int c = 0; c < NC; c++) {
                hs[(size_t)grow * OUTC + c * 16 + lr] = __float2half(acc[c][r] * sc);
            }
        }
    }
}

// ---------------- Aggregate CH=128: wave/node, 8B/lane gathers = 2 rows/instr ------
// hf = lane>>5 picks edge parity; sl = lane&31 covers ch [4sl,4sl+4).
// 16 edges per iteration, 8 VMEM in flight; fold halves via shfl_xor(32).
template<bool RELU>
__global__ __launch_bounds__(256) void aggregate128_kernel(
        const __half* __restrict__ hs, const int* __restrict__ row_off,
        const int* __restrict__ deg, const int* __restrict__ ssrc,
        const float* __restrict__ dinv, const float* __restrict__ bias,
        float* __restrict__ out) {
    int node = (blockIdx.x * 256 + threadIdx.x) >> 6;
    int lane = threadIdx.x & 63;
    if (node >= N_NODES) return;
    int beg = row_off[node];
    int d   = deg[node];
    float di = dinv[node];
    int hf = lane >> 5, sl = lane & 31;
    const float2* Hq = (const float2*)hs;        // [N][32] 8B chunks (4 halves)
    float4 acc = make_float4(0.f, 0.f, 0.f, 0.f);
    for (int j = 0; j < d; j += 16) {
        int s[8]; float2 v[8];
#pragma unroll
        for (int u = 0; u < 8; u++) {
            int i = j + 2 * u + hf;
            s[u] = ssrc[beg + ((i < d) ? i : (d - 1))];
        }
#pragma unroll
        for (int u = 0; u < 8; u++) v[u] = Hq[(size_t)s[u] * 32 + sl];
#pragma unroll
        for (int u = 0; u < 8; u++) {
            if (j + 2 * u + hf < d) {
                float2 f0 = __half22float2(((const __half2*)&v[u])[0]);
                float2 f1 = __half22float2(((const __half2*)&v[u])[1]);
                acc.x += f0.x; acc.y += f0.y; acc.z += f1.x; acc.w += f1.y;
            }
        }
    }
    acc.x += __shfl_xor(acc.x, 32, 64);
    acc.y += __shfl_xor(acc.y, 32, 64);
    acc.z += __shfl_xor(acc.z, 32, 64);
    acc.w += __shfl_xor(acc.w, 32, 64);
    if (hf == 0) {
        float2 sv = Hq[(size_t)node * 32 + sl];  // self-loop
        float2 f0 = __half22float2(((const __half2*)&sv)[0]);
        float2 f1 = __half22float2(((const __half2*)&sv)[1]);
        float4 b = ((const float4*)bias)[sl];
        float4 o;
        o.x = fmaf(di, acc.x + f0.x, b.x);
        o.y = fmaf(di, acc.y + f0.y, b.y);
        o.z = fmaf(di, acc.z + f1.x, b.z);
        o.w = fmaf(di, acc.w + f1.y, b.w);
        if (RELU) {
            o.x = fmaxf(o.x, 0.f); o.y = fmaxf(o.y, 0.f);
            o.z = fmaxf(o.z, 0.f); o.w = fmaxf(o.w, 0.f);
        }
        ((float4*)out)[(size_t)node * 32 + sl] = o;
    }
}

// ---------------- Aggregate CH=64: wave/node, 8B/lane gathers = 4 rows/instr -------
// qt = lane>>4 picks edge offset 0..3; sl = lane&15 covers ch [4sl,4sl+4).
// 32 edges per iteration, 8 VMEM in flight; fold via shfl_xor(16), shfl_xor(32).
__global__ __launch_bounds__(256) void aggregate64_kernel(
        const __half* __restrict__ hs, const int* __restrict__ row_off,
        const int* __restrict__ deg, const int* __restrict__ ssrc,
        const float* __restrict__ dinv, const float* __restrict__ bias,
        float* __restrict__ out) {
    int node = (blockIdx.x * 256 + threadIdx.x) >> 6;
    int lane = threadIdx.x & 63;
    if (node >= N_NODES) return;
    int beg = row_off[node];
    int d   = deg[node];
    float di = dinv[node];
    int qt = lane >> 4, sl = lane & 15;
    const float2* Hq = (const float2*)hs;        // [N][16] 8B chunks
    float4 acc = make_float4(0.f, 0.f, 0.f, 0.f);
    for (int j = 0; j < d; j += 32) {
        int s[8]; float2 v[8];
#pragma unroll
        for (int u = 0; u < 8; u++) {
            int i = j + 4 * u + qt;
            s[u] = ssrc[beg + ((i < d) ? i : (d - 1))];
        }
#pragma unroll
        for (int u = 0; u < 8; u++) v[u] = Hq[(size_t)s[u] * 16 + sl];
#pragma unroll
        for (int u = 0; u < 8; u++) {
            if (j + 4 * u + qt < d) {
                float2 f0 = __half22float2(((const __half2*)&v[u])[0]);
                float2 f1 = __half22float2(((const __half2*)&v[u])[1]);
                acc.x += f0.x; acc.y += f0.y; acc.z += f1.x; acc.w += f1.y;
            }
        }
    }
    acc.x += __shfl_xor(acc.x, 16, 64);
    acc.y += __shfl_xor(acc.y, 16, 64);
    acc.z += __shfl_xor(acc.z, 16, 64);
    acc.w += __shfl_xor(acc.w, 16, 64);
    acc.x += __shfl_xor(acc.x, 32, 64);
    acc.y += __shfl_xor(acc.y, 32, 64);
    acc.z += __shfl_xor(acc.z, 32, 64);
    acc.w += __shfl_xor(acc.w, 32, 64);
    if (lane < 16) {
        float2 sv = Hq[(size_t)node * 16 + sl];  // self-loop
        float2 f0 = __half22float2(((const __half2*)&sv)[0]);
        float2 f1 = __half22float2(((const __half2*)&sv)[1]);
        float4 b = ((const float4*)bias)[sl];
        float4 o;
        o.x = fmaf(di, acc.x + f0.x, b.x);
        o.y = fmaf(di, acc.y + f0.y, b.y);
        o.z = fmaf(di, acc.z + f1.x, b.z);
        o.w = fmaf(di, acc.w + f1.y, b.w);
        ((float4*)out)[(size_t)node * 16 + sl] = o;
    }
}

// ---------------- launch ----------------

extern "C" void kernel_launch(void* const* d_in, const int* in_sizes, int n_in,
                              void* d_out, int out_size, void* d_ws, size_t ws_size,
                              hipStream_t stream) {
    const float* x  = (const float*)d_in[0];   // [N,128]
    const int*   ei = (const int*)d_in[1];     // [2,E]
    const float* W1 = (const float*)d_in[2];   // [128,128]
    const float* b1 = (const float*)d_in[3];   // [128]
    const float* W2 = (const float*)d_in[4];   // [128,64]
    const float* b2 = (const float*)d_in[5];   // [64]
    float* out = (float*)d_out;                // [N,64]

    const int* src = ei;
    const int* dst = ei + N_EDGES;

    char* p = (char*)d_ws;
    size_t off = 0;
    auto alloc = [&](size_t bytes) { void* q = p + off; off += (bytes + 255) & ~(size_t)255; return q; };
    float*    dinv    = (float*)   alloc(N_NODES * 4);
    int*      deg     = (int*)     alloc(N_NODES * 4);
    int*      row_off = (int*)     alloc(N_NODES * 4);
    int*      gcur    = (int*)     alloc(NBIN * 4);
    int*      parts   = (int*)     alloc(64 * 4);
    int*      ssrc    = (int*)     alloc(N_EDGES * 4);
    unsigned* ebin    = (unsigned*)alloc((size_t)NBIN * CAP * 4);   // 4.0 MB
    __bf16*   w1hi    = (__bf16*)  alloc(128 * 128 * 2);
    __bf16*   w1lo    = (__bf16*)  alloc(128 * 128 * 2);
    __bf16*   w2hi    = (__bf16*)  alloc(128 * 64 * 2);
    __bf16*   w2lo    = (__bf16*)  alloc(128 * 64 * 2);
    __half*   hs1     = (__half*)  alloc((size_t)N_NODES * 128 * 2);
    __half*   hs2     = (__half*)  alloc((size_t)N_NODES * 64 * 2);
    float*    x2      = (float*)   alloc((size_t)N_NODES * 128 * 4);

    const int nb_scan = (N_NODES + 1023) / 1024;       // 49

    hipMemsetAsync(gcur, 0, NBIN * sizeof(int), stream);
    bin_scatter_kernel<<<NB_SCAT, 256, 0, stream>>>(src, dst, gcur, ebin);
    bin_count_kernel<<<NBIN, 256, 0, stream>>>(ebin, gcur, deg);
    scan_part_kernel<<<nb_scan, 256, 0, stream>>>(deg, parts);
    scan_blocks_kernel<<<1, 64, 0, stream>>>(parts, nb_scan);
    scan_final_kernel<<<nb_scan, 256, 0, stream>>>(deg, parts, row_off, dinv);
    bin_fill_kernel<<<NBIN, 256, 0, stream>>>(ebin, gcur, row_off, ssrc);

    wprep_kernel<128><<<8, 256, 0, stream>>>(W1, w1hi, w1lo);
    wprep_kernel<64> <<<4, 256, 0, stream>>>(W2, w2hi, w2lo);

    // layer 1: hs1 = fp16(dinv*(x@W1)); x2 = relu(dinv*(self+sum) + b1)
    gemm_mfma_kernel<128><<<(N_NODES + 63) / 64, 256, 0, stream>>>(x, w1hi, w1lo, dinv, hs1);
    aggregate128_kernel<true><<<(N_NODES * 64 + 255) / 256, 256, 0, stream>>>(
        hs1, row_off, deg, ssrc, dinv, b1, x2);

    // layer 2: hs2 = fp16(dinv*(x2@W2)); out = dinv*(self+sum) + b2
    gemm_mfma_kernel<64><<<(N_NODES + 63) / 64, 256, 0, stream>>>(x2, w2hi, w2lo, dinv, hs2);
    aggregate64_kernel<<<(N_NODES * 64 + 255) / 256, 256, 0, stream>>>(
        hs2, row_off, deg, ssrc, dinv, b2, out);
}